// Round 1
// baseline (1020.555 us; speedup 1.0000x reference)
//
#include <hip/hip_runtime.h>

// PepEmbedding fused: out[b,h,:] = soft_threshold(emb[x[b,h],:], s[x[b,h],:])
// soft_threshold(v,s) = sign(v) * relu(|v| - sigmoid(s))
//
// BATCH=16384, HIST=50, HIDDEN=128, NUM_ITEM=1e6
// 819,200 rows of 128 f32. One thread per float4 => 32 threads/row.

#define NROWS   (16384 * 50)
#define VEC_PER_ROW 32          // 128 floats / 4

__device__ __forceinline__ float soft_thresh(float v, float s) {
    float sig = 1.0f / (1.0f + __expf(-s));
    float a = fabsf(v) - sig;
    return (a > 0.0f) ? copysignf(a, v) : 0.0f;
}

__global__ __launch_bounds__(256) void pep_embed_kernel(
    const int* __restrict__ x,
    const float4* __restrict__ emb,   // [NUM_ITEM][32] float4
    const float4* __restrict__ s,     // [NUM_ITEM][32] float4
    float4* __restrict__ out)         // [NROWS][32] float4
{
    int t = blockIdx.x * blockDim.x + threadIdx.x;
    int row = t >> 5;          // which lookup
    int lane = t & 31;         // which float4 within the row
    if (row >= NROWS) return;

    long long idx = (long long)x[row];
    long long src = idx * VEC_PER_ROW + lane;

    float4 v  = emb[src];
    float4 th = s[src];

    float4 r;
    r.x = soft_thresh(v.x, th.x);
    r.y = soft_thresh(v.y, th.y);
    r.z = soft_thresh(v.z, th.z);
    r.w = soft_thresh(v.w, th.w);

    out[(long long)row * VEC_PER_ROW + lane] = r;
}

extern "C" void kernel_launch(void* const* d_in, const int* in_sizes, int n_in,
                              void* d_out, int out_size, void* d_ws, size_t ws_size,
                              hipStream_t stream) {
    const int*    x   = (const int*)d_in[0];
    const float4* emb = (const float4*)d_in[1];
    const float4* s   = (const float4*)d_in[2];
    float4*       out = (float4*)d_out;

    const int total_threads = NROWS * VEC_PER_ROW;   // 26,214,400
    const int block = 256;
    const int grid = (total_threads + block - 1) / block;  // 102,400

    pep_embed_kernel<<<grid, block, 0, stream>>>(x, emb, s, out);
}